// Round 10
// baseline (99.750 us; speedup 1.0000x reference)
//
#include <hip/hip_runtime.h>
#include <math.h>
#include <string.h>

#define HH 2048
#define WW 2048
#define TSC 128
#define TSR 32
#define NBX (WW / TSC)                 // 16
#define NBY (HH / TSR)                 // 64
#define NINT1 ((NBX - 2) * (NBY - 2))  // 868
#define NBND1 (NBX * NBY - NINT1)      // 156

// fused-kernel LDS geometry (floats)
#define LST0 144
#define LST1 140
#define LST2 136

struct W3 { float wA[17][5]; float wC[17][5]; float wB[17]; float knA, knB, knC; };
struct Wts { float w[17][5]; float knorm; };   // fallback path

// angle index a: 0 -> -10deg, 1 -> 0deg, 2 -> +10deg
__host__ __device__ constexpr int js_fn(int a, int i) {
  return (a == 1) ? 2
       : (a == 2) ? ((i < 3) ? 0 : (i < 9) ? 1 : (i < 14) ? 2 : 3)
                  : ((i < 3) ? 3 : (i < 8) ? 2 : (i < 14) ? 1 : 0);
}
__host__ __device__ constexpr int nt_fn(int a, int i) {
  return (a == 1) ? 1 : (i == 8) ? 3 : 2;
}

__device__ __forceinline__ float fastrcp(float x) {
#if __has_builtin(__builtin_amdgcn_rcpf)
  return __builtin_amdgcn_rcpf(x);
#else
  return 1.0f / x;
#endif
}

// =============== FUSED interior kernel: 3 passes in one tile ===============
// buf0: D0 = Y-X over rows [y0-24,y0+56) x cols [x0-8,x0+136)  (80 x 144)
// buf1: D1 over rows [y0-16,y0+48) x D1cols [x0-4,x0+132), stored col+2 shift
// buf2 (alias buf0): D2 rows [y0-8,y0+40) x D2cols [x0-2,x0+130), col+2 shift
// Interior tiles: every intermediate pixel has N == knorm -> no N reads.
__global__ __launch_bounds__(256, 2)
void fused_int(const float* __restrict__ Xg, const float* __restrict__ Yg,
               float* __restrict__ Out, W3 w)
{
  __shared__ float buf0[80 * LST0];   // 46080 B
  __shared__ float buf1[64 * LST1];   // 35840 B  (total 80 KiB -> 2 blocks/CU)
  float* buf2 = buf0;                 // 48*136 <= 80*144, buf0 dead after pass A

  const int bid = blockIdx.x, nwg = gridDim.x;
  const int wg = ((nwg & 7) == 0) ? ((bid & 7) * (nwg >> 3) + (bid >> 3)) : bid;
  const int bz = wg / NINT1;
  const int t0 = wg - bz * NINT1;
  const int bx = 1 + t0 / (NBY - 2);
  const int by = 1 + t0 % (NBY - 2);       // by-fastest: vertical halo L2 hits

  const int tid = threadIdx.x;
  const int x0 = bx * TSC, y0 = by * TSR;
  const size_t img = (size_t)bz * ((size_t)HH * WW);

  // ---- stage: D0 = Y - X (unchecked; window provably in-bounds) ----
#pragma unroll
  for (int s = 0; s < 12; ++s) {
    const int idx = s * 256 + tid;
    if (idx < 80 * 36) {
      const int r = idx / 36, c4 = idx - r * 36;
      const size_t g = img + (size_t)(y0 - 24 + r) * WW + (x0 - 8 + c4 * 4);
      const float4 xv = *(const float4*)(Xg + g);
      const float4 yv = *(const float4*)(Yg + g);
      *(float4*)&buf0[r * LST0 + c4 * 4] =
          make_float4(yv.x - xv.x, yv.y - xv.y, yv.z - xv.z, yv.w - xv.w);
    }
  }
  __syncthreads();

  // ---- pass A (-10deg): D1 = cen - conv_norm(D0), 64 x 136 -> buf1 ----
#pragma unroll 1
  for (int tt = tid; tt < 544; tt += 256) {        // 16 rg x 34 cg
    const int rg = tt / 34, cg = tt - rg * 34;
    const int r0 = rg * 4, c0 = cg * 4;
    float acc[4][4] = {};
#pragma unroll
    for (int rr = 0; rr < 20; ++rr) {
      const float* lp = &buf0[(r0 + rr) * LST0 + c0];
      const float4 w0 = *(const float4*)(lp);
      const float4 w1 = *(const float4*)(lp + 4);
      const float4 w2 = *(const float4*)(lp + 8);
      const float win[8] = {w0.z, w0.w, w1.x, w1.y, w1.z, w1.w, w2.x, w2.y};
#pragma unroll
      for (int t = 0; t < 4; ++t) {
        const int i = rr - t;
        if (i >= 0 && i <= 16) {
          const int js = js_fn(0, i), nt = nt_fn(0, i);
#pragma unroll
          for (int jj = 0; jj < nt; ++jj) {
            const float wv = w.wA[i][js + jj];
#pragma unroll
            for (int c = 0; c < 4; ++c)
              acc[t][c] = fmaf(wv, win[c + js + jj], acc[t][c]);
          }
        }
      }
    }
#pragma unroll
    for (int t = 0; t < 4; ++t) {
      const float4 cen = *(const float4*)&buf0[(r0 + t + 8) * LST0 + c0 + 4];
      *(float2*)&buf1[(r0 + t) * LST1 + c0 + 2] =
          make_float2(cen.x - acc[t][0], cen.y - acc[t][1]);
      *(float2*)&buf1[(r0 + t) * LST1 + c0 + 4] =
          make_float2(cen.z - acc[t][2], cen.w - acc[t][3]);
    }
  }
  __syncthreads();

  // ---- pass B (0deg, vertical 17-tap): D2, 48 x 132 -> buf2 ----
#pragma unroll 1
  for (int tt = tid; tt < 396; tt += 256) {        // 12 rg x 33 cg
    const int rg = tt / 33, cg = tt - rg * 33;
    const int r0 = rg * 4, c0 = cg * 4;
    float acc[4][4] = {};
#pragma unroll
    for (int rr = 0; rr < 20; ++rr) {
      const float4 win = *(const float4*)&buf1[(r0 + rr) * LST1 + c0 + 4];
#pragma unroll
      for (int t = 0; t < 4; ++t) {
        const int i = rr - t;
        if (i >= 0 && i <= 16) {
          const float wv = w.wB[i];
          acc[t][0] = fmaf(wv, win.x, acc[t][0]);
          acc[t][1] = fmaf(wv, win.y, acc[t][1]);
          acc[t][2] = fmaf(wv, win.z, acc[t][2]);
          acc[t][3] = fmaf(wv, win.w, acc[t][3]);
        }
      }
    }
#pragma unroll
    for (int t = 0; t < 4; ++t) {
      const float4 cen = *(const float4*)&buf1[(r0 + t + 8) * LST1 + c0 + 4];
      *(float2*)&buf2[(r0 + t) * LST2 + c0 + 2] =
          make_float2(cen.x - acc[t][0], cen.y - acc[t][1]);
      *(float2*)&buf2[(r0 + t) * LST2 + c0 + 4] =
          make_float2(cen.z - acc[t][2], cen.w - acc[t][3]);
    }
  }
  __syncthreads();

  // ---- pass C (+10deg): X3 = y - cen2 + conv_norm(D2), 32 x 128 ----
  {
    const int tg = tid >> 5, tc = tid & 31;        // 8 rg x 32 cg = 256 exactly
    const int r0 = tg * 4, c0 = tc * 4;
    float acc[4][4] = {};
#pragma unroll
    for (int rr = 0; rr < 20; ++rr) {
      const float* lp = &buf2[(r0 + rr) * LST2 + c0];
      const float4 w0 = *(const float4*)(lp);
      const float4 w1 = *(const float4*)(lp + 4);
      const float4 w2 = *(const float4*)(lp + 8);
      const float win[8] = {w0.z, w0.w, w1.x, w1.y, w1.z, w1.w, w2.x, w2.y};
#pragma unroll
      for (int t = 0; t < 4; ++t) {
        const int i = rr - t;
        if (i >= 0 && i <= 16) {
          const int js = js_fn(2, i), nt = nt_fn(2, i);
#pragma unroll
          for (int jj = 0; jj < nt; ++jj) {
            const float wv = w.wC[i][js + jj];
#pragma unroll
            for (int c = 0; c < 4; ++c)
              acc[t][c] = fmaf(wv, win[c + js + jj], acc[t][c]);
          }
        }
      }
    }
#pragma unroll
    for (int t = 0; t < 4; ++t) {
      const int gy = y0 + r0 + t, gx = x0 + c0;
      const float4 cen = *(const float4*)&buf2[(r0 + t + 8) * LST2 + c0 + 4];
      const float4 yv = *(const float4*)(Yg + img + (size_t)gy * WW + gx);
      *(float4*)(Out + img + (size_t)gy * WW + gx) = make_float4(
          yv.x - cen.x + acc[t][0], yv.y - cen.y + acc[t][1],
          yv.z - cen.z + acc[t][2], yv.w - cen.w + acc[t][3]);
    }
  }
}

// =============== FUSED boundary kernel: checked + N-normalized ===============
__global__ __launch_bounds__(256, 2)
void fused_bnd(const float* __restrict__ Xg, const float* __restrict__ Yg,
               const float* __restrict__ Nn, float* __restrict__ Out, W3 w)
{
  __shared__ float buf0[80 * LST0];
  __shared__ float buf1[64 * LST1];
  float* buf2 = buf0;

  const int u = blockIdx.x;
  int bx, by;
  if (u < NBX)          { bx = u;       by = 0; }
  else if (u < 2 * NBX) { bx = u - NBX; by = NBY - 1; }
  else { const int v = u - 2 * NBX; by = 1 + (v >> 1); bx = (v & 1) ? NBX - 1 : 0; }
  const int bz = blockIdx.y;

  const int tid = threadIdx.x;
  const int x0 = bx * TSC, y0 = by * TSR;
  const size_t img = (size_t)bz * ((size_t)HH * WW);
  const float* N0 = Nn;
  const float* N1 = Nn + (size_t)HH * WW;
  const float* N2 = Nn + 2 * (size_t)HH * WW;

  // ---- checked staging of D0, zero-filled OOB ----
#pragma unroll
  for (int s = 0; s < 12; ++s) {
    const int idx = s * 256 + tid;
    if (idx < 80 * 36) {
      const int r = idx / 36, c4 = idx - r * 36;
      const int gy = y0 - 24 + r;
      const int gx = x0 - 8 + c4 * 4;
      float4 v = make_float4(0.f, 0.f, 0.f, 0.f);
      if (gy >= 0 && gy < HH) {
        const float* xr = Xg + img + (size_t)gy * WW;
        const float* yr = Yg + img + (size_t)gy * WW;
        if (gx >= 0 && gx + 4 <= WW) {
          const float4 xv = *(const float4*)(xr + gx);
          const float4 yv = *(const float4*)(yr + gx);
          v = make_float4(yv.x - xv.x, yv.y - xv.y, yv.z - xv.z, yv.w - xv.w);
        } else {
          float tv[4] = {0.f, 0.f, 0.f, 0.f};
#pragma unroll
          for (int e = 0; e < 4; ++e) {
            const int gxe = gx + e;
            if (gxe >= 0 && gxe < WW) tv[e] = yr[gxe] - xr[gxe];
          }
          v = make_float4(tv[0], tv[1], tv[2], tv[3]);
        }
      }
      *(float4*)&buf0[r * LST0 + c4 * 4] = v;
    }
  }
  __syncthreads();

  // ---- pass A with per-pixel N0 ----
#pragma unroll 1
  for (int tt = tid; tt < 544; tt += 256) {
    const int rg = tt / 34, cg = tt - rg * 34;
    const int r0 = rg * 4, c0 = cg * 4;
    float acc[4][4] = {};
#pragma unroll
    for (int rr = 0; rr < 20; ++rr) {
      const float* lp = &buf0[(r0 + rr) * LST0 + c0];
      const float4 w0 = *(const float4*)(lp);
      const float4 w1 = *(const float4*)(lp + 4);
      const float4 w2 = *(const float4*)(lp + 8);
      const float win[8] = {w0.z, w0.w, w1.x, w1.y, w1.z, w1.w, w2.x, w2.y};
#pragma unroll
      for (int t = 0; t < 4; ++t) {
        const int i = rr - t;
        if (i >= 0 && i <= 16) {
          const int js = js_fn(0, i), nt = nt_fn(0, i);
#pragma unroll
          for (int jj = 0; jj < nt; ++jj) {
            const float wv = w.wA[i][js + jj];
#pragma unroll
            for (int c = 0; c < 4; ++c)
              acc[t][c] = fmaf(wv, win[c + js + jj], acc[t][c]);
          }
        }
      }
    }
#pragma unroll
    for (int t = 0; t < 4; ++t) {
      const int gy = y0 - 16 + r0 + t;
      const bool rok = (gy >= 0) && (gy < HH);
      const float4 cen = *(const float4*)&buf0[(r0 + t + 8) * LST0 + c0 + 4];
      const float cenv[4] = {cen.x, cen.y, cen.z, cen.w};
      float d[4];
#pragma unroll
      for (int c = 0; c < 4; ++c) {
        const int gxc = x0 - 4 + c0 + c;
        const bool ok = rok && (gxc >= 0) && (gxc < WW);
        float r = 0.0f;
        if (ok) {
          const float n = N0[(size_t)gy * WW + gxc];
          r = cenv[c] - acc[t][c] * w.knA * fastrcp(n);
        }
        d[c] = r;
      }
      *(float2*)&buf1[(r0 + t) * LST1 + c0 + 2] = make_float2(d[0], d[1]);
      *(float2*)&buf1[(r0 + t) * LST1 + c0 + 4] = make_float2(d[2], d[3]);
    }
  }
  __syncthreads();

  // ---- pass B with per-pixel N1 ----
#pragma unroll 1
  for (int tt = tid; tt < 396; tt += 256) {
    const int rg = tt / 33, cg = tt - rg * 33;
    const int r0 = rg * 4, c0 = cg * 4;
    float acc[4][4] = {};
#pragma unroll
    for (int rr = 0; rr < 20; ++rr) {
      const float4 win = *(const float4*)&buf1[(r0 + rr) * LST1 + c0 + 4];
#pragma unroll
      for (int t = 0; t < 4; ++t) {
        const int i = rr - t;
        if (i >= 0 && i <= 16) {
          const float wv = w.wB[i];
          acc[t][0] = fmaf(wv, win.x, acc[t][0]);
          acc[t][1] = fmaf(wv, win.y, acc[t][1]);
          acc[t][2] = fmaf(wv, win.z, acc[t][2]);
          acc[t][3] = fmaf(wv, win.w, acc[t][3]);
        }
      }
    }
#pragma unroll
    for (int t = 0; t < 4; ++t) {
      const int gy = y0 - 8 + r0 + t;
      const bool rok = (gy >= 0) && (gy < HH);
      const float4 cen = *(const float4*)&buf1[(r0 + t + 8) * LST1 + c0 + 4];
      const float cenv[4] = {cen.x, cen.y, cen.z, cen.w};
      float d[4];
#pragma unroll
      for (int c = 0; c < 4; ++c) {
        const int gxc = x0 - 2 + c0 + c;
        const bool ok = rok && (gxc >= 0) && (gxc < WW);
        float r = 0.0f;
        if (ok) {
          const float n = N1[(size_t)gy * WW + gxc];
          r = cenv[c] - acc[t][c] * w.knB * fastrcp(n);
        }
        d[c] = r;
      }
      *(float2*)&buf2[(r0 + t) * LST2 + c0 + 2] = make_float2(d[0], d[1]);
      *(float2*)&buf2[(r0 + t) * LST2 + c0 + 4] = make_float2(d[2], d[3]);
    }
  }
  __syncthreads();

  // ---- pass C with per-pixel N2 (output pixels always in-image) ----
  {
    const int tg = tid >> 5, tc = tid & 31;
    const int r0 = tg * 4, c0 = tc * 4;
    float acc[4][4] = {};
#pragma unroll
    for (int rr = 0; rr < 20; ++rr) {
      const float* lp = &buf2[(r0 + rr) * LST2 + c0];
      const float4 w0 = *(const float4*)(lp);
      const float4 w1 = *(const float4*)(lp + 4);
      const float4 w2 = *(const float4*)(lp + 8);
      const float win[8] = {w0.z, w0.w, w1.x, w1.y, w1.z, w1.w, w2.x, w2.y};
#pragma unroll
      for (int t = 0; t < 4; ++t) {
        const int i = rr - t;
        if (i >= 0 && i <= 16) {
          const int js = js_fn(2, i), nt = nt_fn(2, i);
#pragma unroll
          for (int jj = 0; jj < nt; ++jj) {
            const float wv = w.wC[i][js + jj];
#pragma unroll
            for (int c = 0; c < 4; ++c)
              acc[t][c] = fmaf(wv, win[c + js + jj], acc[t][c]);
          }
        }
      }
    }
#pragma unroll
    for (int t = 0; t < 4; ++t) {
      const int gy = y0 + r0 + t, gx = x0 + c0;
      const float4 cen = *(const float4*)&buf2[(r0 + t + 8) * LST2 + c0 + 4];
      const float4 yv = *(const float4*)(Yg + img + (size_t)gy * WW + gx);
      const float4 nv = *(const float4*)(N2 + (size_t)gy * WW + gx);
      *(float4*)(Out + img + (size_t)gy * WW + gx) = make_float4(
          yv.x - cen.x + acc[t][0] * w.knC * fastrcp(nv.x),
          yv.y - cen.y + acc[t][1] * w.knC * fastrcp(nv.y),
          yv.z - cen.z + acc[t][2] * w.knC * fastrcp(nv.z),
          yv.w - cen.w + acc[t][3] * w.knC * fastrcp(nv.w));
    }
  }
}

// ===================== fallback path (r9, dense-capable) =====================
__global__ __launch_bounds__(256)
void diff_kernel(const float* __restrict__ X, const float* __restrict__ Y,
                 float* __restrict__ D, int n4)
{
  const int stride = gridDim.x * 256;
  for (int i = blockIdx.x * 256 + threadIdx.x; i < n4; i += stride) {
    const float4 x = ((const float4*)X)[i];
    const float4 y = ((const float4*)Y)[i];
    ((float4*)D)[i] = make_float4(y.x - x.x, y.y - x.y, y.z - x.z, y.w - x.w);
  }
}

template <int MODE>
__global__ __launch_bounds__(256, 3)
void conv_dense(const float* __restrict__ P0, const float* __restrict__ P1,
                const float* __restrict__ Nrm, float* __restrict__ Out, Wts wts)
{
  constexpr int LSTR = 148, LCW = 36, XOFF = 8, CH = 48 * LCW;
  __shared__ float lds[48 * 148];
  const int bx = blockIdx.x, by = blockIdx.y, bz = blockIdx.z;
  const int tid = threadIdx.x;
  const int x0 = bx * TSC, y0 = by * TSR;
  const size_t img = (size_t)bz * ((size_t)HH * WW);
  const float* A = P0 + img;
#pragma unroll
  for (int s = 0; s < (CH + 255) / 256; ++s) {
    const int idx = s * 256 + tid;
    if (idx < CH) {
      const int r = idx / LCW, c4 = idx - r * LCW;
      const int gy = y0 - 8 + r, gx = x0 - XOFF + c4 * 4;
      float4 v = make_float4(0.f, 0.f, 0.f, 0.f);
      if (gy >= 0 && gy < HH) {
        const float* ar = A + (size_t)gy * WW;
        if (gx >= 0 && gx + 4 <= WW) v = *(const float4*)(ar + gx);
        else {
          float tv[4] = {0.f, 0.f, 0.f, 0.f};
#pragma unroll
          for (int e = 0; e < 4; ++e) {
            const int gxe = gx + e;
            if (gxe >= 0 && gxe < WW) tv[e] = ar[gxe];
          }
          v = make_float4(tv[0], tv[1], tv[2], tv[3]);
        }
      }
      *(float4*)&lds[r * LSTR + c4 * 4] = v;
    }
  }
  __syncthreads();
  const int tc = tid & 31, tg = tid >> 5, lc = tc * 4;
  float acc[4][4] = {};
#pragma unroll
  for (int rr = 0; rr < 20; ++rr) {
    const float* lp = &lds[(tg * 4 + rr) * LSTR];
    const float4 w0 = *(const float4*)(lp + 4 + lc);
    const float4 w1 = *(const float4*)(lp + 8 + lc);
    const float4 w2 = *(const float4*)(lp + 12 + lc);
    const float win[8] = {w0.z, w0.w, w1.x, w1.y, w1.z, w1.w, w2.x, w2.y};
#pragma unroll
    for (int t = 0; t < 4; ++t) {
      const int i = rr - t;
      if (i >= 0 && i <= 16) {
#pragma unroll
        for (int jj = 0; jj < 5; ++jj) {
          const float wv = wts.w[i][jj];
#pragma unroll
          for (int c = 0; c < 4; ++c)
            acc[t][c] = fmaf(wv, win[c + jj], acc[t][c]);
        }
      }
    }
  }
  float* Ob = Out + img;
  const int gx = x0 + lc;
  const float kn = wts.knorm;
#pragma unroll
  for (int t = 0; t < 4; ++t) {
    const int yo = y0 + tg * 4 + t;
    const float4 cv = *(const float4*)&lds[(tg * 4 + t + 8) * LSTR + XOFF + lc];
    const float4 nv = *(const float4*)(Nrm + (size_t)yo * WW + gx);
    const float a0 = acc[t][0] * kn * fastrcp(nv.x);
    const float a1 = acc[t][1] * kn * fastrcp(nv.y);
    const float a2 = acc[t][2] * kn * fastrcp(nv.z);
    const float a3 = acc[t][3] * kn * fastrcp(nv.w);
    float4 o;
    if (MODE == 2) {
      const float4 yv = *(const float4*)(P1 + img + (size_t)yo * WW + gx);
      o = make_float4(yv.x - cv.x + a0, yv.y - cv.y + a1,
                      yv.z - cv.z + a2, yv.w - cv.w + a3);
    } else {
      o = make_float4(cv.x - a0, cv.y - a1, cv.z - a2, cv.w - a3);
    }
    *(float4*)(Ob + (size_t)yo * WW + gx) = o;
  }
}

// ---------------- host-side replication of _build_kernels ----------------
static void rotate33(const double* src, double* dst, double ang_deg) {
  const int n = 33;
  const double t = ang_deg * 3.14159265358979323846 / 180.0;
  const double cs = cos(t), sn = sin(t);
  for (int y = 0; y < n; ++y) {
    for (int x = 0; x < n; ++x) {
      const double y0 = y - 16.0, x0 = x - 16.0;
      const double sy = cs * y0 + sn * x0 + 16.0;
      const double sx = -sn * y0 + cs * x0 + 16.0;
      const double fy = floor(sy), fx = floor(sx);
      const int y0i = (int)fy, x0i = (int)fx;
      const double wy = sy - fy, wx = sx - fx;
      double o = 0.0;
      for (int dy = 0; dy < 2; ++dy)
        for (int dx = 0; dx < 2; ++dx) {
          const int yy = y0i + dy, xx = x0i + dx;
          if (yy < 0 || yy >= n || xx < 0 || xx >= n) continue;
          const double wgt = (dy ? wy : 1.0 - wy) * (dx ? wx : 1.0 - wx);
          o += wgt * src[yy * n + xx];
        }
      dst[y * n + x] = o;
    }
  }
}

static void build_K(float K[3][17][5]) {
  const double angs[3] = {-10.0, 0.0, 10.0};
  double base[33 * 33], rot[33 * 33];
  for (int i = 0; i < 33 * 33; ++i) base[i] = 0.0;
  for (int y = 0; y < 33; ++y) base[y * 33 + 16] = 1.0;
  for (int a = 0; a < 3; ++a) {
    if (a == 1) memcpy(rot, base, sizeof(rot));
    else        rotate33(base, rot, angs[a]);
    double k17[17][17];
    for (int y = 0; y < 17; ++y)
      for (int x = 0; x < 17; ++x) k17[y][x] = rot[(y + 8) * 33 + (x + 8)];
    int r = 0, c = 0;
    for (int y = 0; y < 17; ++y) { bool nz = false; for (int x = 0; x < 17; ++x) if (k17[y][x] != 0.0) nz = true; r += nz; }
    for (int x = 0; x < 17; ++x) { bool nz = false; for (int y = 0; y < 17; ++y) if (k17[y][x] != 0.0) nz = true; c += nz; }
    r = r / 2 * 2; c = c / 2 * 2;
    const int kh = r + 1, kw = c + 1;
    for (int y = 0; y < 17; ++y)
      for (int x = 0; x < 5; ++x) K[a][y][x] = 0.0f;
    if (kh <= 17 && kw <= 5) {
      const int oh = (17 - kh) / 2, ow = (5 - kw) / 2;
      for (int y = 0; y < kh; ++y)
        for (int x = 0; x < kw; ++x)
          K[a][oh + y][ow + x] = (float)k17[8 - r / 2 + y][8 - c / 2 + x];
    }
  }
}

static int pick_mode(int a, const float K[17][5]) {
  for (int i = 0; i < 17; ++i) {
    const int js = js_fn(a, i), nt = nt_fn(a, i);
    for (int j = 0; j < 5; ++j)
      if ((j < js || j >= js + nt) && K[i][j] != 0.0f) return 1;
  }
  return 0;
}

extern "C" void kernel_launch(void* const* d_in, const int* in_sizes, int n_in,
                              void* d_out, int out_size, void* d_ws, size_t ws_size,
                              hipStream_t stream) {
  const float* X  = (const float*)d_in[0];
  const float* Y  = (const float*)d_in[1];
  const float* Nn = (const float*)d_in[3];
  float* out = (float*)d_out;
  float* tmp = (float*)d_ws;
  const size_t HW = (size_t)HH * WW;
  const int B = in_sizes[0] / (int)HW;   // 2

  float K[3][17][5];
  build_K(K);
  double ks[3];
  for (int a = 0; a < 3; ++a) {
    ks[a] = 0.0;
    for (int i = 0; i < 17; ++i)
      for (int j = 0; j < 5; ++j) ks[a] += K[a][i][j];
  }
  const int dense = pick_mode(0, K[0]) | pick_mode(1, K[1]) | pick_mode(2, K[2]);

  if (!dense) {
    W3 w;
    for (int i = 0; i < 17; ++i)
      for (int j = 0; j < 5; ++j) {
        w.wA[i][j] = (float)(K[0][i][j] / ks[0]);
        w.wC[i][j] = (float)(K[2][i][j] / ks[2]);
      }
    for (int i = 0; i < 17; ++i) w.wB[i] = (float)(K[1][i][2] / ks[1]);
    w.knA = (float)ks[0]; w.knB = (float)ks[1]; w.knC = (float)ks[2];

    fused_int<<<dim3(NINT1 * B), dim3(256), 0, stream>>>(X, Y, out, w);
    fused_bnd<<<dim3(NBND1, B), dim3(256), 0, stream>>>(X, Y, Nn, out, w);
  } else {
    // dense fallback: diff + 3 checked conv passes (r9-proven structure)
    Wts w[3];
    for (int a = 0; a < 3; ++a) {
      for (int i = 0; i < 17; ++i)
        for (int j = 0; j < 5; ++j) w[a].w[i][j] = (float)(K[a][i][j] / ks[a]);
      w[a].knorm = (float)ks[a];
    }
    const int n4 = (int)(B * HW / 4);
    const int dg = (n4 + 255) / 256;
    diff_kernel<<<dim3(dg > 8192 ? 8192 : dg), dim3(256), 0, stream>>>(X, Y, tmp, n4);
    dim3 g(NBX, NBY, B), blk(256);
    conv_dense<1><<<g, blk, 0, stream>>>(tmp, nullptr, Nn,          out, w[0]);
    conv_dense<1><<<g, blk, 0, stream>>>(out, nullptr, Nn + HW,     tmp, w[1]);
    conv_dense<2><<<g, blk, 0, stream>>>(tmp, Y,       Nn + 2 * HW, out, w[2]);
  }
}